// Round 2
// 344.081 us; speedup vs baseline: 1.0357x; 1.0357x over previous
//
#include <hip/hip_runtime.h>
#include <hip/hip_bf16.h>
#include <math.h>

typedef __attribute__((ext_vector_type(8))) short short8;
typedef __attribute__((ext_vector_type(4))) float f32x4;

#define VOCAB 8192
#define NSAMP 8192
#define INTER 4352
#define EMB   512

// ---- workspace layout (bytes) ----
#define OFF_CNT    0            // 8192*4   = 32768
#define OFF_A1     32768        // 4352*4   = 17408
#define OFF_M1     50176        // 17408
#define OFF_A2     67584        // 2048
#define OFF_M2     69632        // 2048
#define OFF_PS1B   71680        // [512][128] f32 = 262144 (region reserved 1 MB)
#define OFF_PS2B   1120256      // [512][128] f32 = 262144
#define OFF_W2B    2168832      // 512*4352*2 = 4456448
#define OFF_HACT   6625280      // 8192*4352*2 = 71303168
#define OFF_H2     77928448     // 8192*512*4 = 16777216

__device__ __forceinline__ float gelu_exact(float x) {
    return 0.5f * x * (1.0f + erff(x * 0.70710678118654752f));
}
__device__ __forceinline__ unsigned short f2bf(float x) {
    __hip_bfloat16 b = __float2bfloat16(x);
    return *reinterpret_cast<unsigned short*>(&b);
}
__device__ __forceinline__ void async16(const unsigned short* g, unsigned short* l) {
    __builtin_amdgcn_global_load_lds(
        (const __attribute__((address_space(1))) void*)g,
        (__attribute__((address_space(3))) void*)l, 16, 0, 0);
}

// ---------------- histogram ----------------
__global__ void k_zero_cnt(int* cnt) {
    cnt[blockIdx.x * 256 + threadIdx.x] = 0;
}
__global__ void k_hist(const int* __restrict__ xt, int* __restrict__ cnt) {
    int n = blockIdx.x * 256 + threadIdx.x;
    atomicAdd(&cnt[xt[n]], 1);
}

// ---------------- BN1 stats: one wave per channel row, fused finalize ------------
__global__ __launch_bounds__(256) void k_stats1(const float* __restrict__ W1,
                                                const int* __restrict__ cnt,
                                                const float* __restrict__ g1,
                                                float* __restrict__ a1,
                                                float* __restrict__ m1) {
    const int t = threadIdx.x, lane = t & 63, w = t >> 6;
    const int row = blockIdx.x * 4 + w;
    const float* wr = W1 + (size_t)row * VOCAB;
    float s1 = 0.f, s2 = 0.f;
    #pragma unroll 8
    for (int it = 0; it < 32; ++it) {
        int v = it * 256 + lane * 4;
        float4 x = *(const float4*)(wr + v);
        int4 c = *(const int4*)(cnt + v);
        float cx = (float)c.x, cy = (float)c.y, cz = (float)c.z, cw = (float)c.w;
        s1 += cx * x.x + cy * x.y + cz * x.z + cw * x.w;
        s2 += cx * x.x * x.x + cy * x.y * x.y + cz * x.z * x.z + cw * x.w * x.w;
    }
    #pragma unroll
    for (int d = 1; d < 64; d <<= 1) {
        s1 += __shfl_xor(s1, d);
        s2 += __shfl_xor(s2, d);
    }
    if (lane == 0) {
        float m = s1 * (1.f / NSAMP);
        float var = s2 * (1.f / NSAMP) - m * m;
        a1[row] = g1[row] * rsqrtf(var + 1e-5f);
        m1[row] = m;
    }
}

// ------- build Hact[v,i] = bf16(gelu(a1*(W1[i,v]-m1)+beta1)), all vocab rows -------
__global__ __launch_bounds__(256) void k_build(const float* __restrict__ W1,
                                               const float* __restrict__ a1,
                                               const float* __restrict__ m1,
                                               const float* __restrict__ beta1,
                                               unsigned short* __restrict__ Hact) {
    const int i0 = blockIdx.x * 64;
    const int v0 = blockIdx.y * 256;
    const int t = threadIdx.x;
    const int c0 = (t & 15) * 4;
    const int vg = (t >> 4) * 4;   // 0..60
    float4 av = *(const float4*)(a1 + i0 + c0);
    float4 mv = *(const float4*)(m1 + i0 + c0);
    float4 bv = *(const float4*)(beta1 + i0 + c0);
    const float* ap = (const float*)&av;
    const float* mp = (const float*)&mv;
    const float* bp = (const float*)&bv;
    #pragma unroll
    for (int vi = 0; vi < 4; ++vi) {
        int vb = v0 + vi * 64 + vg;
        float wf[4][4];
        #pragma unroll
        for (int j = 0; j < 4; ++j)
            *(float4*)&wf[j][0] = *(const float4*)(W1 + (size_t)(i0 + c0 + j) * VOCAB + vb);
        #pragma unroll
        for (int k = 0; k < 4; ++k) {
            ushort4 o;
            o.x = f2bf(gelu_exact(ap[0] * (wf[0][k] - mp[0]) + bp[0]));
            o.y = f2bf(gelu_exact(ap[1] * (wf[1][k] - mp[1]) + bp[1]));
            o.z = f2bf(gelu_exact(ap[2] * (wf[2][k] - mp[2]) + bp[2]));
            o.w = f2bf(gelu_exact(ap[3] * (wf[3][k] - mp[3]) + bp[3]));
            *(ushort4*)&Hact[(size_t)(vb + k) * INTER + i0 + c0] = o;
        }
    }
}

// ---------------- W2 fp32 -> bf16 ----------------
__global__ void k_w2bf(const float* __restrict__ W2, unsigned short* __restrict__ W2b) {
    int idx = (blockIdx.x * 256 + threadIdx.x) * 4;
    float4 w = *(const float4*)(W2 + idx);
    ushort4 u;
    u.x = f2bf(w.x); u.y = f2bf(w.y); u.z = f2bf(w.z); u.w = f2bf(w.w);
    *(ushort4*)(W2b + idx) = u;
}

// ------- full-K GEMM: h2 = Hact[8192,4352] * W2b[512,4352]^T (bf16 MFMA) ---------
// Tile 128M x 128N, grid 256 blocks (m = bid>>2, n = bid&3) -> 1 block/CU, no split-K.
// 512 threads = 8 waves (2x4), each wave 64M x 32N. K-step 64, LDS double-buffered
// (2 x (16+16) KB = 64 KB): STAGE(next) issued before COMPUTE(cur) so the 4
// global_load_lds fly under the 16 MFMAs (T3-minimum 2-phase). XOR-swizzled LDS
// groups (group g of row r at g ^ (r&7)) — conflict-free ds_read_b128.
// Epilogue: write h2 once + cnt-weighted BN2 partial stats (sum w*h, w*h^2 per col)
// reduced over kq lanes, stored as ps[col][mblk*2+wr] ([512][128]).
__global__ __launch_bounds__(512) void k_gemm(const unsigned short* __restrict__ A,
                                              const unsigned short* __restrict__ B,
                                              const int* __restrict__ cnt,
                                              float* __restrict__ h2,
                                              float* __restrict__ ps1,
                                              float* __restrict__ ps2) {
    __shared__ __align__(16) unsigned short sA[2][128 * 64];
    __shared__ __align__(16) unsigned short sB[2][128 * 64];
    const int bid = blockIdx.x;
    const int mblk = bid >> 2;
    const int nblk = bid & 3;       // XCD x (bid%8) sees a single nblk -> B-slice L2-resident
    const int m0 = mblk * 128;
    const int n0 = nblk * 128;
    const int t = threadIdx.x;
    const int lane = t & 63;
    const int wave = t >> 6;                     // 0..7
    const int wr = wave >> 2, wc = wave & 3;     // 2x4 waves, each 64M x 32N
    const int mq = lane & 15, kq = lane >> 4;
    const int srow = lane >> 3;                  // staging row within 8-row group
    const int sgrp = lane & 7;                   // staging 16B-group
    const int scol = (sgrp ^ srow) * 8;          // swizzled global column (shorts)
    const int swz = mq & 7;                      // fragment-read swizzle

    const unsigned short* Ab = A + (size_t)(m0 + wave * 16 + srow) * INTER + scol;
    const unsigned short* Bb = B + (size_t)(n0 + wave * 16 + srow) * INTER + scol;

    f32x4 acc[4][2];
    #pragma unroll
    for (int r = 0; r < 4; ++r)
        #pragma unroll
        for (int c = 0; c < 2; ++c) acc[r][c] = (f32x4){0.f, 0.f, 0.f, 0.f};

    auto stage = [&](int buf, int k0) {
        async16(Ab + k0,                         &sA[buf][(wave * 16) * 64]);
        async16(Ab + (size_t)8 * INTER + k0,     &sA[buf][(wave * 16 + 8) * 64]);
        async16(Bb + k0,                         &sB[buf][(wave * 16) * 64]);
        async16(Bb + (size_t)8 * INTER + k0,     &sB[buf][(wave * 16 + 8) * 64]);
    };
    auto compute = [&](int buf) {
        #pragma unroll
        for (int kk = 0; kk < 64; kk += 32) {
            const int gbase = kq + (kk >> 3);
            short8 af[4], bfr[2];
            #pragma unroll
            for (int r = 0; r < 4; ++r)
                af[r] = *(const short8*)&sA[buf][(wr * 64 + r * 16 + mq) * 64 + ((gbase ^ swz) * 8)];
            #pragma unroll
            for (int c = 0; c < 2; ++c)
                bfr[c] = *(const short8*)&sB[buf][(wc * 32 + c * 16 + mq) * 64 + ((gbase ^ swz) * 8)];
            #pragma unroll
            for (int r = 0; r < 4; ++r)
                #pragma unroll
                for (int c = 0; c < 2; ++c)
                    acc[r][c] = __builtin_amdgcn_mfma_f32_16x16x32_bf16(af[r], bfr[c], acc[r][c], 0, 0, 0);
        }
    };

    stage(0, 0);
    __syncthreads();                 // compiler drains vmcnt(0) here
    for (int ti = 0; ti < 67; ++ti) {
        stage((ti + 1) & 1, (ti + 1) * 64);   // next tile in flight...
        compute(ti & 1);                       // ...under current tile's MFMAs
        __syncthreads();             // vmcnt(0)+barrier: next buf ready, cur buf free
    }
    compute(1);                      // tile 67

    // ---- epilogue: h2 store + fused cnt-weighted BN2 partial stats ----
    float s1[2] = {0.f, 0.f}, s2[2] = {0.f, 0.f};
    #pragma unroll
    for (int r = 0; r < 4; ++r) {
        const int rowb = m0 + wr * 64 + r * 16 + kq * 4;
        int4 cw = *(const int4*)(cnt + rowb);
        float w0 = (float)cw.x, w1 = (float)cw.y, w2 = (float)cw.z, w3 = (float)cw.w;
        #pragma unroll
        for (int c = 0; c < 2; ++c) {
            const int col = n0 + wc * 32 + c * 16 + mq;
            float v0 = acc[r][c][0], v1 = acc[r][c][1], v2 = acc[r][c][2], v3 = acc[r][c][3];
            h2[(size_t)(rowb + 0) * EMB + col] = v0;
            h2[(size_t)(rowb + 1) * EMB + col] = v1;
            h2[(size_t)(rowb + 2) * EMB + col] = v2;
            h2[(size_t)(rowb + 3) * EMB + col] = v3;
            s1[c] += w0 * v0 + w1 * v1 + w2 * v2 + w3 * v3;
            s2[c] += w0 * v0 * v0 + w1 * v1 * v1 + w2 * v2 * v2 + w3 * v3 * v3;
        }
    }
    #pragma unroll
    for (int c = 0; c < 2; ++c) {
        s1[c] += __shfl_xor(s1[c], 16);
        s2[c] += __shfl_xor(s2[c], 16);
        s1[c] += __shfl_xor(s1[c], 32);
        s2[c] += __shfl_xor(s2[c], 32);
    }
    if (lane < 16) {
        const int slot = mblk * 2 + wr;
        #pragma unroll
        for (int c = 0; c < 2; ++c) {
            const int col = n0 + wc * 32 + c * 16 + mq;
            ps1[(size_t)col * 128 + slot] = s1[c];
            ps2[(size_t)col * 128 + slot] = s2[c];
        }
    }
}

// one wave per channel e: reduce 128 block-partials, fused finalize
__global__ __launch_bounds__(256) void k_stats2f(const float* __restrict__ ps1,
                                                 const float* __restrict__ ps2,
                                                 const float* __restrict__ g2,
                                                 float* __restrict__ a2,
                                                 float* __restrict__ m2) {
    const int lane = threadIdx.x & 63;
    const int e = blockIdx.x * 4 + (threadIdx.x >> 6);   // 128 blocks
    float s1 = ps1[(size_t)e * 128 + lane] + ps1[(size_t)e * 128 + 64 + lane];
    float s2 = ps2[(size_t)e * 128 + lane] + ps2[(size_t)e * 128 + 64 + lane];
    #pragma unroll
    for (int d = 1; d < 64; d <<= 1) {
        s1 += __shfl_xor(s1, d);
        s2 += __shfl_xor(s2, d);
    }
    if (lane == 0) {
        float m = s1 * (1.f / NSAMP);
        float var = s2 * (1.f / NSAMP) - m * m;
        a2[e] = g2[e] * rsqrtf(var + 1e-5f);
        m2[e] = m;
    }
}

// ---------------- final gather + BN2 + gelu ----------------
__global__ __launch_bounds__(256) void k_final(const float* __restrict__ h2,
                                               const int* __restrict__ xt,
                                               const float* __restrict__ a2,
                                               const float* __restrict__ m2,
                                               const float* __restrict__ beta2,
                                               float* __restrict__ out) {
    const int t = threadIdx.x;
    const int n = blockIdx.x * 2 + (t >> 7);
    const int e = (t & 127) * 4;
    const int v = xt[n];
    float4 h = *(const float4*)(h2 + (size_t)v * EMB + e);
    float4 a = *(const float4*)(a2 + e);
    float4 m = *(const float4*)(m2 + e);
    float4 b = *(const float4*)(beta2 + e);
    float4 o;
    o.x = gelu_exact(a.x * (h.x - m.x) + b.x);
    o.y = gelu_exact(a.y * (h.y - m.y) + b.y);
    o.z = gelu_exact(a.z * (h.z - m.z) + b.z);
    o.w = gelu_exact(a.w * (h.w - m.w) + b.w);
    *(float4*)(out + (size_t)n * EMB + e) = o;
}

extern "C" void kernel_launch(void* const* d_in, const int* in_sizes, int n_in,
                              void* d_out, int out_size, void* d_ws, size_t ws_size,
                              hipStream_t stream) {
    const int* xt      = (const int*)d_in[0];
    const float* W1    = (const float*)d_in[1];
    // d_in[2] = b1 (cancels in BN), d_in[6] = b2 (cancels in BN)
    const float* g1    = (const float*)d_in[3];
    const float* beta1 = (const float*)d_in[4];
    const float* W2    = (const float*)d_in[5];
    const float* g2    = (const float*)d_in[7];
    const float* beta2 = (const float*)d_in[8];
    float* out = (float*)d_out;

    char* ws = (char*)d_ws;
    int*   cnt  = (int*)  (ws + OFF_CNT);
    float* a1   = (float*)(ws + OFF_A1);
    float* m1   = (float*)(ws + OFF_M1);
    float* a2   = (float*)(ws + OFF_A2);
    float* m2   = (float*)(ws + OFF_M2);
    float* ps1b = (float*)(ws + OFF_PS1B);
    float* ps2b = (float*)(ws + OFF_PS2B);
    unsigned short* W2b  = (unsigned short*)(ws + OFF_W2B);
    unsigned short* Hact = (unsigned short*)(ws + OFF_HACT);
    float* h2   = (float*)(ws + OFF_H2);

    k_zero_cnt<<<32, 256, 0, stream>>>(cnt);
    k_hist<<<32, 256, 0, stream>>>(xt, cnt);
    k_stats1<<<1088, 256, 0, stream>>>(W1, cnt, g1, a1, m1);
    k_build<<<dim3(68, 32), 256, 0, stream>>>(W1, a1, m1, beta1, Hact);
    k_w2bf<<<2176, 256, 0, stream>>>(W2, W2b);
    k_gemm<<<256, 512, 0, stream>>>(Hact, W2b, cnt, h2, ps1b, ps2b);
    k_stats2f<<<128, 256, 0, stream>>>(ps1b, ps2b, g2, a2, m2);
    k_final<<<4096, 256, 0, stream>>>(h2, xt, a2, m2, beta2, out);
}